// Round 1
// baseline (5160.207 us; speedup 1.0000x reference)
//
#include <hip/hip_runtime.h>
#include <hip/hip_bf16.h>

#define TSEQ  512
#define BATCH 64
#define HIDN  512
#define EMBD  100
#define NWG   64

typedef __attribute__((ext_vector_type(8))) short short8;
typedef __attribute__((ext_vector_type(4))) float f32x4;
typedef unsigned int u32;

// ---- workspace layout (bytes) ----
#define A_OFF   0ull                 // 512*64*512 bf16 = 33,554,432
#define HD_OFF  33554432ull          // 512*64*512 bf16 = 33,554,432
#define HB_OFF  67108864ull          // 2 * 64*512 bf16 = 131,072
#define CNT_OFF 67239936ull          // 256
#define KEY_OFF 67240192ull          // 6400 * 4 = 25,600
#define DW_OFF  67265792ull          // 112*512*2 = 114,688
#define ZERO_SPAN 156928ull          // HB..KEY end (hb + cnt + key)

static __device__ __forceinline__ unsigned short f2bfbits(float f) {
    u32 u = __float_as_uint(f);
    u32 r = (u + 0x7fffu + ((u >> 16) & 1u)) >> 16;   // round-to-nearest-even
    return (unsigned short)r;
}

static __device__ __forceinline__ float sigf(float x) {
    return 1.0f / (1.0f + __expf(-x));
}

// ---------------- K1: dec_w -> bf16 (padded to 112 rows with zeros) ----------
__global__ void k_dw(const float* __restrict__ dw, unsigned short* __restrict__ dwb) {
    int i = blockIdx.x * 256 + threadIdx.x;            // 57,344 = 112*512
    float v = (i < EMBD * HIDN) ? dw[i] : 0.0f;
    dwb[i] = f2bfbits(v);
}

// ---------------- K2: embedding gather -> bf16 A[t][b][k] --------------------
__global__ void k_embed(const int* __restrict__ x, const float* __restrict__ emb,
                        unsigned short* __restrict__ A) {
    int g = blockIdx.x * 256 + threadIdx.x;            // 2,097,152 = T*B*64
    int k8 = g & 63;
    int bt = g >> 6;                                   // t*64 + b
    int b  = bt & 63;
    int t  = bt >> 6;
    int row = x[b * TSEQ + t];
    const float4* src = reinterpret_cast<const float4*>(emb + (size_t)row * HIDN + k8 * 8);
    float4 v0 = src[0], v1 = src[1];
    short8 s;
    s[0] = (short)f2bfbits(v0.x); s[1] = (short)f2bfbits(v0.y);
    s[2] = (short)f2bfbits(v0.z); s[3] = (short)f2bfbits(v0.w);
    s[4] = (short)f2bfbits(v1.x); s[5] = (short)f2bfbits(v1.y);
    s[6] = (short)f2bfbits(v1.z); s[7] = (short)f2bfbits(v1.w);
    *reinterpret_cast<short8*>(A + (size_t)g * 8) = s;
}

// ---------------- K3: persistent LSTM+BN+dropout ----------------------------
// 64 WGs x 512 threads. WG wg owns h-columns [wg*8, wg*8+8).
// Wave w (0..7): mb = w&3 (16-row M block), kh = w>>2 (K half: 0=emb, 1=h).
// B fragments (static weights) live in registers: bfr[16][2] = 128 VGPRs.
// Pointwise/BN: wave w handles column jl=w, lane = batch row.
__launch_bounds__(512)
__global__ void k_lstm(const float* __restrict__ wih, const float* __restrict__ whh,
                       const float* __restrict__ bih, const float* __restrict__ bhh,
                       const float* __restrict__ gamma, const float* __restrict__ beta,
                       const float* __restrict__ mask,
                       const unsigned short* __restrict__ A,
                       unsigned short* __restrict__ hbuf,
                       unsigned short* __restrict__ hd,
                       u32* __restrict__ cnt) {
    const int tid  = threadIdx.x;
    const int wg   = blockIdx.x;
    const int lane = tid & 63;
    const int w    = tid >> 6;        // wave 0..7
    const int mb   = w & 3;
    const int kh   = w >> 2;

    __shared__ float gbuf[2][64][33];                       // partial gates (kh halves)
    __shared__ __align__(16) unsigned short hstage[64][8];
    __shared__ __align__(16) unsigned short hdstage[64][8];

    const int l15 = lane & 15;
    const int lk8 = (lane >> 4) * 8;

    // ---- load static B fragments into registers (once) ----
    const float* wsrc = kh ? whh : wih;
    short8 bfr[16][2];
    #pragma unroll
    for (int kk = 0; kk < 16; ++kk) {
        #pragma unroll
        for (int nb = 0; nb < 2; ++nb) {
            int nl   = nb * 16 + l15;                 // local gate col 0..31
            int gate = nl >> 3, jl = nl & 7;
            int ng   = gate * HIDN + wg * 8 + jl;     // row of w_ih/w_hh [4H, H]
            int kl   = kk * 32 + lk8;                 // 0..511 within this K half
            const float* p = wsrc + (size_t)ng * HIDN + kl;
            short8 bb;
            #pragma unroll
            for (int e = 0; e < 8; ++e) bb[e] = (short)f2bfbits(p[e]);
            bfr[kk][nb] = bb;
        }
    }

    // ---- pointwise-role constants: this thread = (column jj, batch lane) ----
    const int jj = wg * 8 + w;
    const float bias_i = bih[jj]          + bhh[jj];
    const float bias_f = bih[512 + jj]    + bhh[512 + jj];
    const float bias_g = bih[1024 + jj]   + bhh[1024 + jj];
    const float bias_o = bih[1536 + jj]   + bhh[1536 + jj];
    const float gam = gamma[jj], bet = beta[jj];
    const float mk  = mask[(size_t)lane * HIDN + jj] * (1.0f / 0.7f);
    float c = 0.0f;

    const int arow = mb * 16 + l15;   // M row for MFMA A-fragment loads

    for (int t = 0; t < TSEQ; ++t) {
        const unsigned short* abase = (kh == 0)
            ? (A    + ((size_t)t * 64 + arow) * HIDN)
            : (hbuf + (size_t)(t & 1) * 32768 + (size_t)arow * HIDN);

        f32x4 acc0 = {0.f, 0.f, 0.f, 0.f};
        f32x4 acc1 = {0.f, 0.f, 0.f, 0.f};
        #pragma unroll
        for (int kk = 0; kk < 16; ++kk) {
            short8 a = *reinterpret_cast<const short8*>(abase + kk * 32 + lk8);
            acc0 = __builtin_amdgcn_mfma_f32_16x16x32_bf16(a, bfr[kk][0], acc0, 0, 0, 0);
            acc1 = __builtin_amdgcn_mfma_f32_16x16x32_bf16(a, bfr[kk][1], acc1, 0, 0, 0);
        }
        #pragma unroll
        for (int r = 0; r < 4; ++r) {
            int row = mb * 16 + (lane >> 4) * 4 + r;
            gbuf[kh][row][l15]      = acc0[r];
            gbuf[kh][row][16 + l15] = acc1[r];
        }
        __syncthreads();

        // ---- LSTM pointwise + BatchNorm (batch = 64 lanes of this wave) ----
        float gi = gbuf[0][lane][w]      + gbuf[1][lane][w]      + bias_i;
        float gf = gbuf[0][lane][8 + w]  + gbuf[1][lane][8 + w]  + bias_f;
        float gg = gbuf[0][lane][16 + w] + gbuf[1][lane][16 + w] + bias_g;
        float go = gbuf[0][lane][24 + w] + gbuf[1][lane][24 + w] + bias_o;
        float iv = sigf(gi), fv = sigf(gf), gv = tanhf(gg), ov = sigf(go);
        c = fv * c + iv * gv;
        float h = ov * tanhf(c);

        float s1 = h, s2 = h * h;
        #pragma unroll
        for (int m = 1; m < 64; m <<= 1) {
            s1 += __shfl_xor(s1, m, 64);
            s2 += __shfl_xor(s2, m, 64);
        }
        float mu  = s1 * (1.0f / 64.0f);
        float var = s2 * (1.0f / 64.0f) - mu * mu;
        float hn  = (h - mu) * rsqrtf(var + 1e-5f) * gam + bet;
        float hdv = hn * mk;

        hstage[lane][w]  = f2bfbits(h);
        hdstage[lane][w] = f2bfbits(hdv);
        __syncthreads();

        if (tid < 64) {   // wave 0 copies staged tiles to global (16B rows)
            short8 hv = *reinterpret_cast<const short8*>(&hstage[tid][0]);
            short8 dv = *reinterpret_cast<const short8*>(&hdstage[tid][0]);
            *reinterpret_cast<short8*>(hbuf + (size_t)((t & 1) ^ 1) * 32768
                                            + (size_t)tid * HIDN + wg * 8) = hv;
            *reinterpret_cast<short8*>(hd + ((size_t)t * 64 + tid) * HIDN + wg * 8) = dv;
        }

        // ---- grid-wide flag sync (h must cross XCDs; device-scope fences) ----
        if (t != TSEQ - 1) {
            __syncthreads();
            if (tid == 0) {
                __threadfence();                       // release h/hd stores
                atomicAdd(cnt, 1u);
                u32 tgt = (u32)NWG * (u32)(t + 1);
                while (__hip_atomic_load(cnt, __ATOMIC_RELAXED,
                                         __HIP_MEMORY_SCOPE_AGENT) < tgt) {
                    __builtin_amdgcn_s_sleep(8);
                }
                __threadfence();                       // acquire others' h
            }
            __syncthreads();
        }
    }
}

// ---------------- K4: decode GEMM + running max (one WG per t) ---------------
__launch_bounds__(256)
__global__ void k_decode(const unsigned short* __restrict__ hd,
                         const unsigned short* __restrict__ dwb,
                         u32* __restrict__ key) {
    const int t    = blockIdx.x;
    const int tid  = threadIdx.x;
    const int lane = tid & 63;
    const int w    = tid >> 6;
    const int l15  = lane & 15;
    const int lk8  = (lane >> 4) * 8;
    const int brow = w * 16 + l15;

    const unsigned short* abase = hd + ((size_t)t * 64 + brow) * HIDN;
    f32x4 acc[7];
    #pragma unroll
    for (int nb = 0; nb < 7; ++nb) acc[nb] = (f32x4){0.f, 0.f, 0.f, 0.f};

    #pragma unroll
    for (int kk = 0; kk < 16; ++kk) {
        short8 a = *reinterpret_cast<const short8*>(abase + kk * 32 + lk8);
        #pragma unroll
        for (int nb = 0; nb < 7; ++nb) {
            short8 b = *reinterpret_cast<const short8*>(
                dwb + (size_t)(nb * 16 + l15) * HIDN + kk * 32 + lk8);
            acc[nb] = __builtin_amdgcn_mfma_f32_16x16x32_bf16(a, b, acc[nb], 0, 0, 0);
        }
    }
    #pragma unroll
    for (int nb = 0; nb < 7; ++nb) {
        int n = nb * 16 + l15;
        if (n < EMBD) {
            #pragma unroll
            for (int r = 0; r < 4; ++r) {
                int b = w * 16 + (lane >> 4) * 4 + r;
                u32 u  = __float_as_uint(acc[nb][r]);
                u32 kv = (u & 0x80000000u) ? ~u : (u | 0x80000000u);  // order-preserving
                atomicMax(&key[b * EMBD + n], kv);
            }
        }
    }
}

// ---------------- K5: inverse transform + decoder bias -----------------------
__global__ void k_final(const u32* __restrict__ key, const float* __restrict__ db,
                        float* __restrict__ out) {
    int i = blockIdx.x * 256 + threadIdx.x;
    if (i < BATCH * EMBD) {
        u32 k = key[i];
        u32 u = (k & 0x80000000u) ? (k & 0x7fffffffu) : ~k;
        out[i] = __uint_as_float(u) + db[i % EMBD];
    }
}

extern "C" void kernel_launch(void* const* d_in, const int* in_sizes, int n_in,
                              void* d_out, int out_size, void* d_ws, size_t ws_size,
                              hipStream_t stream) {
    const int*   x   = (const int*)d_in[0];
    const float* emb = (const float*)d_in[1];
    const float* wih = (const float*)d_in[2];
    const float* whh = (const float*)d_in[3];
    const float* bih = (const float*)d_in[4];
    const float* bhh = (const float*)d_in[5];
    const float* gam = (const float*)d_in[6];
    const float* bet = (const float*)d_in[7];
    const float* dw  = (const float*)d_in[8];
    const float* db  = (const float*)d_in[9];
    const float* msk = (const float*)d_in[10];

    char* ws = (char*)d_ws;
    unsigned short* A   = (unsigned short*)(ws + A_OFF);
    unsigned short* hd  = (unsigned short*)(ws + HD_OFF);
    unsigned short* hb  = (unsigned short*)(ws + HB_OFF);
    u32*            cnt = (u32*)(ws + CNT_OFF);
    u32*            key = (u32*)(ws + KEY_OFF);
    unsigned short* dwb = (unsigned short*)(ws + DW_OFF);

    hipMemsetAsync(ws + HB_OFF, 0, ZERO_SPAN, stream);      // h ping-pong + counter + keys
    k_dw    <<<224,  256, 0, stream>>>(dw, dwb);
    k_embed <<<8192, 256, 0, stream>>>(x, emb, A);
    k_lstm  <<<NWG,  512, 0, stream>>>(wih, whh, bih, bhh, gam, bet, msk, A, hb, hd, cnt);
    k_decode<<<TSEQ, 256, 0, stream>>>(hd, dwb, key);
    k_final <<<25,   256, 0, stream>>>(key, db, (float*)d_out);
}

// Round 2
// 3281.029 us; speedup vs baseline: 1.5727x; 1.5727x over previous
//
#include <hip/hip_runtime.h>
#include <hip/hip_bf16.h>

#define TSEQ  512
#define BATCH 64
#define HIDN  512
#define EMBD  100
#define NWG   64

typedef __attribute__((ext_vector_type(8))) short short8;
typedef __attribute__((ext_vector_type(4))) float f32x4;
typedef unsigned int u32;

// ---- workspace layout (bytes) ----
#define A_OFF   0ull                 // 512*64*512 bf16 = 33,554,432
#define HD_OFF  33554432ull          // 512*64*512 bf16 = 33,554,432
#define HB_OFF  67108864ull          // 2 * 64*512 bf16 = 131,072
#define CNT_OFF 67239936ull          // 256
#define KEY_OFF 67240192ull          // 6400 * 4 = 25,600
#define DW_OFF  67265792ull          // 112*512*2 = 114,688
#define ZERO_SPAN 156928ull          // HB..KEY end (hb + cnt + key)

static __device__ __forceinline__ unsigned short f2bfbits(float f) {
    u32 u = __float_as_uint(f);
    u32 r = (u + 0x7fffu + ((u >> 16) & 1u)) >> 16;   // round-to-nearest-even
    return (unsigned short)r;
}

static __device__ __forceinline__ float sigf(float x) {
    return __builtin_amdgcn_rcpf(1.0f + __expf(-x));
}
static __device__ __forceinline__ float tanhfast(float x) {
    float t = __expf(-2.0f * fabsf(x));               // in (0,1], no overflow
    float r = (1.0f - t) * __builtin_amdgcn_rcpf(1.0f + t);
    return copysignf(r, x);
}

// ---------------- K1: dec_w -> bf16 (padded to 112 rows with zeros) ----------
__global__ void k_dw(const float* __restrict__ dw, unsigned short* __restrict__ dwb) {
    int i = blockIdx.x * 256 + threadIdx.x;            // 57,344 = 112*512
    float v = (i < EMBD * HIDN) ? dw[i] : 0.0f;
    dwb[i] = f2bfbits(v);
}

// ---------------- K2: embedding gather -> bf16 A[t][b][k] --------------------
__global__ void k_embed(const int* __restrict__ x, const float* __restrict__ emb,
                        unsigned short* __restrict__ A) {
    int g = blockIdx.x * 256 + threadIdx.x;            // 2,097,152 = T*B*64
    int k8 = g & 63;
    int bt = g >> 6;                                   // t*64 + b
    int b  = bt & 63;
    int t  = bt >> 6;
    int row = x[b * TSEQ + t];
    const float4* src = reinterpret_cast<const float4*>(emb + (size_t)row * HIDN + k8 * 8);
    float4 v0 = src[0], v1 = src[1];
    short8 s;
    s[0] = (short)f2bfbits(v0.x); s[1] = (short)f2bfbits(v0.y);
    s[2] = (short)f2bfbits(v0.z); s[3] = (short)f2bfbits(v0.w);
    s[4] = (short)f2bfbits(v1.x); s[5] = (short)f2bfbits(v1.y);
    s[6] = (short)f2bfbits(v1.z); s[7] = (short)f2bfbits(v1.w);
    *reinterpret_cast<short8*>(A + (size_t)g * 8) = s;
}

// ---------------- K3: persistent LSTM+BN+dropout ----------------------------
// 64 WGs x 512 threads. WG wg owns h-columns [wg*8, wg*8+8).
// Wave w (0..7): mb = w&3 (16-row M block), kh = w>>2 (K half: 0=emb, 1=h).
// Static weight fragments live in registers (128 VGPR-equiv).
// Pointwise/BN: wave w handles column jj=wg*8+w, lane = batch row.
// Cross-WG h exchange: device-scope (sc1) stores/loads through L3 + relaxed
// atomic flag counter. NO __threadfence (no L2 writeback/invalidate).
__launch_bounds__(512)
__global__ void k_lstm(const float* __restrict__ wih, const float* __restrict__ whh,
                       const float* __restrict__ bih, const float* __restrict__ bhh,
                       const float* __restrict__ gamma, const float* __restrict__ beta,
                       const float* __restrict__ mask,
                       const unsigned short* __restrict__ A,
                       unsigned short* __restrict__ hbuf,
                       unsigned short* __restrict__ hd,
                       u32* __restrict__ cnt) {
    const int tid  = threadIdx.x;
    const int wg   = blockIdx.x;
    const int lane = tid & 63;
    const int w    = tid >> 6;        // wave 0..7
    const int mb   = w & 3;
    const int kh   = w >> 2;

    __shared__ float gbuf[2][64][33];                       // partial gates (kh halves)
    __shared__ __align__(16) unsigned short hstage[64][8];
    __shared__ __align__(16) unsigned short hdstage[2][64][8];

    const int l15 = lane & 15;
    const int lk8 = (lane >> 4) * 8;

    // ---- load static B fragments into registers (once) ----
    const float* wsrc = kh ? whh : wih;
    short8 bfr[16][2];
    #pragma unroll
    for (int kk = 0; kk < 16; ++kk) {
        #pragma unroll
        for (int nb = 0; nb < 2; ++nb) {
            int nl   = nb * 16 + l15;                 // local gate col 0..31
            int gate = nl >> 3, jl = nl & 7;
            int ng   = gate * HIDN + wg * 8 + jl;     // row of w_ih/w_hh [4H, H]
            int kl   = kk * 32 + lk8;                 // 0..511 within this K half
            const float* p = wsrc + (size_t)ng * HIDN + kl;
            short8 bb;
            #pragma unroll
            for (int e = 0; e < 8; ++e) bb[e] = (short)f2bfbits(p[e]);
            bfr[kk][nb] = bb;
        }
    }

    // ---- pointwise-role constants ----
    const int jj = wg * 8 + w;
    const float bias_i = bih[jj]          + bhh[jj];
    const float bias_f = bih[512 + jj]    + bhh[512 + jj];
    const float bias_g = bih[1024 + jj]   + bhh[1024 + jj];
    const float bias_o = bih[1536 + jj]   + bhh[1536 + jj];
    const float gam = gamma[jj], bet = beta[jj];
    const float mk  = mask[(size_t)lane * HIDN + jj] * (1.0f / 0.7f);
    float c = 0.0f;

    const int arow = mb * 16 + l15;   // M row for MFMA A-fragment loads

    // ---- prologue: gbuf[1] (h half) = 0; gbuf[0] = A[0] @ Wih^T ----
    {
        float* g1 = &gbuf[1][0][0];
        for (int i = tid; i < 64 * 33; i += 512) g1[i] = 0.0f;
    }
    __syncthreads();
    if (kh == 0) {
        const unsigned short* abase = A + (size_t)arow * HIDN;
        f32x4 acc0 = {0.f,0.f,0.f,0.f}, acc1 = {0.f,0.f,0.f,0.f};
        #pragma unroll
        for (int kk = 0; kk < 16; ++kk) {
            short8 a = *reinterpret_cast<const short8*>(abase + kk * 32 + lk8);
            acc0 = __builtin_amdgcn_mfma_f32_16x16x32_bf16(a, bfr[kk][0], acc0, 0, 0, 0);
            acc1 = __builtin_amdgcn_mfma_f32_16x16x32_bf16(a, bfr[kk][1], acc1, 0, 0, 0);
        }
        #pragma unroll
        for (int r = 0; r < 4; ++r) {
            int row = mb * 16 + (lane >> 4) * 4 + r;
            gbuf[0][row][l15]      = acc0[r];
            gbuf[0][row][16 + l15] = acc1[r];
        }
    }
    __syncthreads();

    for (int s = 0; s < TSEQ; ++s) {
        // ---- pointwise: gates(s) -> c, h(s+1) (critical path) ----
        float gi = gbuf[0][lane][w]      + gbuf[1][lane][w]      + bias_i;
        float gf = gbuf[0][lane][8 + w]  + gbuf[1][lane][8 + w]  + bias_f;
        float gg = gbuf[0][lane][16 + w] + gbuf[1][lane][16 + w] + bias_g;
        float go = gbuf[0][lane][24 + w] + gbuf[1][lane][24 + w] + bias_o;
        float iv = sigf(gi), fv = sigf(gf), gv = tanhfast(gg), ov = sigf(go);
        c = fv * c + iv * gv;
        float h = ov * tanhfast(c);
        hstage[lane][w] = f2bfbits(h);
        __syncthreads();                                        // [A]

        const int sb = (s + 1) & 1;

        // ---- wave0: publish h(s+1) device-coherent + signal (critical) ----
        if (s != TSEQ - 1 && w == 0) {
            short8 hv = *reinterpret_cast<const short8*>(&hstage[lane][0]);
            unsigned short* dst = hbuf + (size_t)sb * 32768 + (size_t)lane * HIDN + wg * 8;
            asm volatile("global_store_dwordx4 %0, %1, off sc1" :: "v"(dst), "v"(hv) : "memory");
            asm volatile("s_waitcnt vmcnt(0)" ::: "memory");
            if (lane == 0) atomicAdd(cnt, 1u);                  // relaxed, agent scope
        }

        // ---- BatchNorm + locked dropout (off critical path) ----
        {
            float s1 = h, s2 = h * h;
            #pragma unroll
            for (int m = 1; m < 64; m <<= 1) {
                s1 += __shfl_xor(s1, m, 64);
                s2 += __shfl_xor(s2, m, 64);
            }
            float mu  = s1 * (1.0f / 64.0f);
            float var = s2 * (1.0f / 64.0f) - mu * mu;
            float hn  = (h - mu) * rsqrtf(var + 1e-5f) * gam + bet;
            hdstage[s & 1][lane][w] = f2bfbits(hn * mk);
        }

        // ---- MFMA for gates(s+1) ----
        if (s != TSEQ - 1) {
            if (kh == 0) {
                // embedding half: no dependence on the sync at all
                const unsigned short* abase = A + ((size_t)(s + 1) * 64 + arow) * HIDN;
                f32x4 acc0 = {0.f,0.f,0.f,0.f}, acc1 = {0.f,0.f,0.f,0.f};
                #pragma unroll
                for (int kk = 0; kk < 16; ++kk) {
                    short8 a = *reinterpret_cast<const short8*>(abase + kk * 32 + lk8);
                    acc0 = __builtin_amdgcn_mfma_f32_16x16x32_bf16(a, bfr[kk][0], acc0, 0, 0, 0);
                    acc1 = __builtin_amdgcn_mfma_f32_16x16x32_bf16(a, bfr[kk][1], acc1, 0, 0, 0);
                }
                #pragma unroll
                for (int r = 0; r < 4; ++r) {
                    int row = mb * 16 + (lane >> 4) * 4 + r;
                    gbuf[0][row][l15]      = acc0[r];
                    gbuf[0][row][16 + l15] = acc1[r];
                }
            } else {
                // h half: wait for all WGs' h(s+1), then coherent-load it
                const u32 tgt = (u32)NWG * (u32)(s + 1);
                u32 v = __hip_atomic_load(cnt, __ATOMIC_RELAXED, __HIP_MEMORY_SCOPE_AGENT);
                while (__builtin_amdgcn_readfirstlane(v) < tgt) {
                    v = __hip_atomic_load(cnt, __ATOMIC_RELAXED, __HIP_MEMORY_SCOPE_AGENT);
                }
                __builtin_amdgcn_sched_barrier(0);
                const unsigned short* hbase = hbuf + (size_t)sb * 32768 + (size_t)arow * HIDN;
                short8 hf[16];
                #pragma unroll
                for (int kk = 0; kk < 16; ++kk) {
                    const unsigned short* p = hbase + kk * 32 + lk8;
                    asm volatile("global_load_dwordx4 %0, %1, off sc1"
                                 : "=v"(hf[kk]) : "v"(p) : "memory");
                }
                asm volatile("s_waitcnt vmcnt(0)" ::: "memory");
                __builtin_amdgcn_sched_barrier(0);
                f32x4 acc0 = {0.f,0.f,0.f,0.f}, acc1 = {0.f,0.f,0.f,0.f};
                #pragma unroll
                for (int kk = 0; kk < 16; ++kk) {
                    acc0 = __builtin_amdgcn_mfma_f32_16x16x32_bf16(hf[kk], bfr[kk][0], acc0, 0, 0, 0);
                    acc1 = __builtin_amdgcn_mfma_f32_16x16x32_bf16(hf[kk], bfr[kk][1], acc1, 0, 0, 0);
                }
                #pragma unroll
                for (int r = 0; r < 4; ++r) {
                    int row = mb * 16 + (lane >> 4) * 4 + r;
                    gbuf[1][row][l15]      = acc0[r];
                    gbuf[1][row][16 + l15] = acc1[r];
                }
            }
        }
        __syncthreads();                                        // [B]

        // ---- wave1 drains hd(s) (reads cross-wave hdstage, post-[B]) ----
        if (w == 1) {
            short8 dv = *reinterpret_cast<const short8*>(&hdstage[s & 1][lane][0]);
            *reinterpret_cast<short8*>(hd + ((size_t)s * 64 + lane) * HIDN + wg * 8) = dv;
        }
    }
}

// ---------------- K4: decode GEMM + running max (one WG per t) ---------------
__launch_bounds__(256)
__global__ void k_decode(const unsigned short* __restrict__ hd,
                         const unsigned short* __restrict__ dwb,
                         u32* __restrict__ key) {
    const int t    = blockIdx.x;
    const int tid  = threadIdx.x;
    const int lane = tid & 63;
    const int w    = tid >> 6;
    const int l15  = lane & 15;
    const int lk8  = (lane >> 4) * 8;
    const int brow = w * 16 + l15;

    const unsigned short* abase = hd + ((size_t)t * 64 + brow) * HIDN;
    f32x4 acc[7];
    #pragma unroll
    for (int nb = 0; nb < 7; ++nb) acc[nb] = (f32x4){0.f, 0.f, 0.f, 0.f};

    #pragma unroll
    for (int kk = 0; kk < 16; ++kk) {
        short8 a = *reinterpret_cast<const short8*>(abase + kk * 32 + lk8);
        #pragma unroll
        for (int nb = 0; nb < 7; ++nb) {
            short8 b = *reinterpret_cast<const short8*>(
                dwb + (size_t)(nb * 16 + l15) * HIDN + kk * 32 + lk8);
            acc[nb] = __builtin_amdgcn_mfma_f32_16x16x32_bf16(a, b, acc[nb], 0, 0, 0);
        }
    }
    #pragma unroll
    for (int nb = 0; nb < 7; ++nb) {
        int n = nb * 16 + l15;
        if (n < EMBD) {
            #pragma unroll
            for (int r = 0; r < 4; ++r) {
                int b = w * 16 + (lane >> 4) * 4 + r;
                u32 u  = __float_as_uint(acc[nb][r]);
                u32 kv = (u & 0x80000000u) ? ~u : (u | 0x80000000u);  // order-preserving
                atomicMax(&key[b * EMBD + n], kv);
            }
        }
    }
}

// ---------------- K5: inverse transform + decoder bias -----------------------
__global__ void k_final(const u32* __restrict__ key, const float* __restrict__ db,
                        float* __restrict__ out) {
    int i = blockIdx.x * 256 + threadIdx.x;
    if (i < BATCH * EMBD) {
        u32 k = key[i];
        u32 u = (k & 0x80000000u) ? (k & 0x7fffffffu) : ~k;
        out[i] = __uint_as_float(u) + db[i % EMBD];
    }
}

extern "C" void kernel_launch(void* const* d_in, const int* in_sizes, int n_in,
                              void* d_out, int out_size, void* d_ws, size_t ws_size,
                              hipStream_t stream) {
    const int*   x   = (const int*)d_in[0];
    const float* emb = (const float*)d_in[1];
    const float* wih = (const float*)d_in[2];
    const float* whh = (const float*)d_in[3];
    const float* bih = (const float*)d_in[4];
    const float* bhh = (const float*)d_in[5];
    const float* gam = (const float*)d_in[6];
    const float* bet = (const float*)d_in[7];
    const float* dw  = (const float*)d_in[8];
    const float* db  = (const float*)d_in[9];
    const float* msk = (const float*)d_in[10];

    char* ws = (char*)d_ws;
    unsigned short* A   = (unsigned short*)(ws + A_OFF);
    unsigned short* hd  = (unsigned short*)(ws + HD_OFF);
    unsigned short* hb  = (unsigned short*)(ws + HB_OFF);
    u32*            cnt = (u32*)(ws + CNT_OFF);
    u32*            key = (u32*)(ws + KEY_OFF);
    unsigned short* dwb = (unsigned short*)(ws + DW_OFF);

    hipMemsetAsync(ws + HB_OFF, 0, ZERO_SPAN, stream);      // h ping-pong + counter + keys
    k_dw    <<<224,  256, 0, stream>>>(dw, dwb);
    k_embed <<<8192, 256, 0, stream>>>(x, emb, A);
    k_lstm  <<<NWG,  512, 0, stream>>>(wih, whh, bih, bhh, gam, bet, msk, A, hb, hd, cnt);
    k_decode<<<TSEQ, 256, 0, stream>>>(hd, dwb, key);
    k_final <<<25,   256, 0, stream>>>(key, db, (float*)d_out);
}

// Round 3
// 2117.656 us; speedup vs baseline: 2.4368x; 1.5494x over previous
//
#include <hip/hip_runtime.h>
#include <hip/hip_bf16.h>

#define TSEQ  512
#define BATCH 64
#define HIDN  512
#define EMBD  100
#define NWG   64

typedef __attribute__((ext_vector_type(8))) short short8;
typedef __attribute__((ext_vector_type(4))) float f32x4;
typedef unsigned int u32;

// ---- workspace layout (bytes) ----
#define A_OFF   0ull                 // 512*64*512 bf16 = 33,554,432
#define HD_OFF  33554432ull          // 512*64*512 bf16 = 33,554,432
#define HB_OFF  67108864ull          // 2 * 64 wg * 64 row * 8 col bf16 = 131,072
#define FLG_OFF 67239936ull          // 64 flags * 64B pad = 4,096
#define KEY_OFF 67244032ull          // 6400 * 4 = 25,600
#define DW_OFF  67269632ull          // 112*512*2 = 114,688
#define ZERO_SPAN 160768ull          // HB + FLG + KEY

static __device__ __forceinline__ unsigned short f2bfbits(float f) {
    u32 u = __float_as_uint(f);
    u32 r = (u + 0x7fffu + ((u >> 16) & 1u)) >> 16;   // round-to-nearest-even
    return (unsigned short)r;
}

static __device__ __forceinline__ float sigf(float x) {
    return __builtin_amdgcn_rcpf(1.0f + __expf(-x));
}
static __device__ __forceinline__ float tanhfast(float x) {
    float t = __expf(-2.0f * fabsf(x));               // in (0,1], no overflow
    float r = (1.0f - t) * __builtin_amdgcn_rcpf(1.0f + t);
    return copysignf(r, x);
}

// ---------------- K1: dec_w -> bf16 (padded to 112 rows with zeros) ----------
__global__ void k_dw(const float* __restrict__ dw, unsigned short* __restrict__ dwb) {
    int i = blockIdx.x * 256 + threadIdx.x;            // 57,344 = 112*512
    float v = (i < EMBD * HIDN) ? dw[i] : 0.0f;
    dwb[i] = f2bfbits(v);
}

// ---------------- K2: embedding gather -> bf16 A[t][b][k] --------------------
__global__ void k_embed(const int* __restrict__ x, const float* __restrict__ emb,
                        unsigned short* __restrict__ A) {
    int g = blockIdx.x * 256 + threadIdx.x;            // 2,097,152 = T*B*64
    int k8 = g & 63;
    int bt = g >> 6;                                   // t*64 + b
    int b  = bt & 63;
    int t  = bt >> 6;
    int row = x[b * TSEQ + t];
    const float4* src = reinterpret_cast<const float4*>(emb + (size_t)row * HIDN + k8 * 8);
    float4 v0 = src[0], v1 = src[1];
    short8 s;
    s[0] = (short)f2bfbits(v0.x); s[1] = (short)f2bfbits(v0.y);
    s[2] = (short)f2bfbits(v0.z); s[3] = (short)f2bfbits(v0.w);
    s[4] = (short)f2bfbits(v1.x); s[5] = (short)f2bfbits(v1.y);
    s[6] = (short)f2bfbits(v1.z); s[7] = (short)f2bfbits(v1.w);
    *reinterpret_cast<short8*>(A + (size_t)g * 8) = s;
}

// ---------------- K3: persistent LSTM+BN+dropout ----------------------------
// 64 WGs x 512 threads. WG wg owns h-columns [wg*8, wg*8+8).
// Wave w (0..7): mb = w&3 (16-row M block), kh = w>>2 (K half: 0=emb, 1=h).
// Static weight fragments live in registers.
// Cross-WG h exchange: h stored per-WG-contiguous [sb][wg][row][8] via sc1
// (device-coherent, through L3), then per-WG padded flag (plain sc1 store).
// Readers: one vector load polls all 64 flags (lane i -> flag[i]); no atomics,
// no fences, no shared hot cacheline.
__launch_bounds__(512)
__global__ void k_lstm(const float* __restrict__ wih, const float* __restrict__ whh,
                       const float* __restrict__ bih, const float* __restrict__ bhh,
                       const float* __restrict__ gamma, const float* __restrict__ beta,
                       const float* __restrict__ mask,
                       const unsigned short* __restrict__ A,
                       unsigned short* __restrict__ hbuf,
                       unsigned short* __restrict__ hd,
                       u32* __restrict__ flg) {
    const int tid  = threadIdx.x;
    const int wg   = blockIdx.x;
    const int lane = tid & 63;
    const int w    = tid >> 6;        // wave 0..7
    const int mb   = w & 3;
    const int kh   = w >> 2;

    __shared__ float gbuf[2][64][33];                       // partial gates (kh halves)
    __shared__ __align__(16) unsigned short hstage[64][8];
    __shared__ __align__(16) unsigned short hdstage[2][64][8];

    const int l15 = lane & 15;
    const int lk8 = (lane >> 4) * 8;

    // ---- load static B fragments into registers (once) ----
    const float* wsrc = kh ? whh : wih;
    short8 bfr[16][2];
    #pragma unroll
    for (int kk = 0; kk < 16; ++kk) {
        #pragma unroll
        for (int nb = 0; nb < 2; ++nb) {
            int nl   = nb * 16 + l15;                 // local gate col 0..31
            int gate = nl >> 3, jl = nl & 7;
            int ng   = gate * HIDN + wg * 8 + jl;     // row of w_ih/w_hh [4H, H]
            int kl   = kk * 32 + lk8;                 // 0..511 within this K half
            const float* p = wsrc + (size_t)ng * HIDN + kl;
            short8 bb;
            #pragma unroll
            for (int e = 0; e < 8; ++e) bb[e] = (short)f2bfbits(p[e]);
            bfr[kk][nb] = bb;
        }
    }

    // ---- pointwise-role constants ----
    const int jj = wg * 8 + w;
    const float bias_i = bih[jj]          + bhh[jj];
    const float bias_f = bih[512 + jj]    + bhh[512 + jj];
    const float bias_g = bih[1024 + jj]   + bhh[1024 + jj];
    const float bias_o = bih[1536 + jj]   + bhh[1536 + jj];
    const float gam = gamma[jj], bet = beta[jj];
    const float mk  = mask[(size_t)lane * HIDN + jj] * (1.0f / 0.7f);
    float c = 0.0f;

    const int arow = mb * 16 + l15;   // M row for MFMA A-fragment loads
    const u32* fp = flg + lane * 16;  // this lane polls flag[lane] (64B padded)

    // ---- prologue: gbuf[1] (h half) = 0; gbuf[0] = A[0] @ Wih^T ----
    {
        float* g1 = &gbuf[1][0][0];
        for (int i = tid; i < 64 * 33; i += 512) g1[i] = 0.0f;
    }
    __syncthreads();
    if (kh == 0) {
        const unsigned short* abase = A + (size_t)arow * HIDN;
        f32x4 acc0 = {0.f,0.f,0.f,0.f}, acc1 = {0.f,0.f,0.f,0.f};
        #pragma unroll
        for (int kk = 0; kk < 16; ++kk) {
            short8 a = *reinterpret_cast<const short8*>(abase + kk * 32 + lk8);
            acc0 = __builtin_amdgcn_mfma_f32_16x16x32_bf16(a, bfr[kk][0], acc0, 0, 0, 0);
            acc1 = __builtin_amdgcn_mfma_f32_16x16x32_bf16(a, bfr[kk][1], acc1, 0, 0, 0);
        }
        #pragma unroll
        for (int r = 0; r < 4; ++r) {
            int row = mb * 16 + (lane >> 4) * 4 + r;
            gbuf[0][row][l15]      = acc0[r];
            gbuf[0][row][16 + l15] = acc1[r];
        }
    }
    __syncthreads();

    for (int s = 0; s < TSEQ; ++s) {
        // ---- pointwise: gates(s) -> c, h(s+1) (critical path) ----
        float gi = gbuf[0][lane][w]      + gbuf[1][lane][w]      + bias_i;
        float gf = gbuf[0][lane][8 + w]  + gbuf[1][lane][8 + w]  + bias_f;
        float gg = gbuf[0][lane][16 + w] + gbuf[1][lane][16 + w] + bias_g;
        float go = gbuf[0][lane][24 + w] + gbuf[1][lane][24 + w] + bias_o;
        float iv = sigf(gi), fv = sigf(gf), gv = tanhfast(gg), ov = sigf(go);
        c = fv * c + iv * gv;
        float h = ov * tanhfast(c);
        hstage[lane][w] = f2bfbits(h);
        __syncthreads();                                        // [A]

        const int sb = (s + 1) & 1;

        // ---- wave0: issue h(s+1) store (device-coherent, WG-contiguous) ----
        if (s != TSEQ - 1 && w == 0) {
            short8 hv = *reinterpret_cast<const short8*>(&hstage[lane][0]);
            unsigned short* dst = hbuf + (size_t)sb * 32768 + (size_t)wg * 512 + lane * 8;
            asm volatile("global_store_dwordx4 %0, %1, off sc1" :: "v"(dst), "v"(hv) : "memory");
        }

        // ---- BatchNorm + locked dropout (hides store-ack / poll wait) ----
        {
            float s1 = h, s2 = h * h;
            #pragma unroll
            for (int m = 1; m < 64; m <<= 1) {
                s1 += __shfl_xor(s1, m, 64);
                s2 += __shfl_xor(s2, m, 64);
            }
            float mu  = s1 * (1.0f / 64.0f);
            float var = s2 * (1.0f / 64.0f) - mu * mu;
            float hn  = (h - mu) * rsqrtf(var + 1e-5f) * gam + bet;
            hdstage[s & 1][lane][w] = f2bfbits(hn * mk);
        }

        // ---- wave0: store-ack, then publish flag (plain sc1, own line) ----
        if (s != TSEQ - 1 && w == 0) {
            asm volatile("s_waitcnt vmcnt(0)" ::: "memory");
            if (lane == 0) {
                u32 fv = (u32)(s + 1);
                const u32* myf = flg + wg * 16;
                asm volatile("global_store_dword %0, %1, off sc1" :: "v"(myf), "v"(fv) : "memory");
            }
        }

        // ---- MFMA for gates(s+1) ----
        if (s != TSEQ - 1) {
            if (kh == 0) {
                // embedding half: no dependence on the sync at all
                const unsigned short* abase = A + ((size_t)(s + 1) * 64 + arow) * HIDN;
                f32x4 acc0 = {0.f,0.f,0.f,0.f}, acc1 = {0.f,0.f,0.f,0.f};
                #pragma unroll
                for (int kk = 0; kk < 16; ++kk) {
                    short8 a = *reinterpret_cast<const short8*>(abase + kk * 32 + lk8);
                    acc0 = __builtin_amdgcn_mfma_f32_16x16x32_bf16(a, bfr[kk][0], acc0, 0, 0, 0);
                    acc1 = __builtin_amdgcn_mfma_f32_16x16x32_bf16(a, bfr[kk][1], acc1, 0, 0, 0);
                }
                #pragma unroll
                for (int r = 0; r < 4; ++r) {
                    int row = mb * 16 + (lane >> 4) * 4 + r;
                    gbuf[0][row][l15]      = acc0[r];
                    gbuf[0][row][16 + l15] = acc1[r];
                }
            } else {
                // h half: poll all 64 flags with one vector load (lane i -> flag[i])
                const u32 tgt = (u32)(s + 1);
                u32 v;
                do {
                    asm volatile("global_load_dword %0, %1, off sc1"
                                 : "=v"(v) : "v"(fp) : "memory");
                    asm volatile("s_waitcnt vmcnt(0)" ::: "memory");
                } while (!__all((int)(v >= tgt)));
                __builtin_amdgcn_sched_barrier(0);
                // load h(s+1): block-contiguous layout [sb][wg'][row][8]
                short8 hf[16];
                #pragma unroll
                for (int kk = 0; kk < 16; ++kk) {
                    const unsigned short* p = hbuf + (size_t)sb * 32768
                        + (size_t)(kk * 4 + (lane >> 4)) * 512 + arow * 8;
                    asm volatile("global_load_dwordx4 %0, %1, off sc1"
                                 : "=v"(hf[kk]) : "v"(p) : "memory");
                }
                asm volatile("s_waitcnt vmcnt(0)" ::: "memory");
                __builtin_amdgcn_sched_barrier(0);
                f32x4 acc0 = {0.f,0.f,0.f,0.f}, acc1 = {0.f,0.f,0.f,0.f};
                #pragma unroll
                for (int kk = 0; kk < 16; ++kk) {
                    acc0 = __builtin_amdgcn_mfma_f32_16x16x32_bf16(hf[kk], bfr[kk][0], acc0, 0, 0, 0);
                    acc1 = __builtin_amdgcn_mfma_f32_16x16x32_bf16(hf[kk], bfr[kk][1], acc1, 0, 0, 0);
                }
                #pragma unroll
                for (int r = 0; r < 4; ++r) {
                    int row = mb * 16 + (lane >> 4) * 4 + r;
                    gbuf[1][row][l15]      = acc0[r];
                    gbuf[1][row][16 + l15] = acc1[r];
                }
            }
        }
        __syncthreads();                                        // [B]

        // ---- wave1 drains hd(s) (reads cross-wave hdstage, post-[B]) ----
        if (w == 1) {
            short8 dv = *reinterpret_cast<const short8*>(&hdstage[s & 1][lane][0]);
            *reinterpret_cast<short8*>(hd + ((size_t)s * 64 + lane) * HIDN + wg * 8) = dv;
        }
    }
}

// ---------------- K4: decode GEMM + running max (one WG per t) ---------------
__launch_bounds__(256)
__global__ void k_decode(const unsigned short* __restrict__ hd,
                         const unsigned short* __restrict__ dwb,
                         u32* __restrict__ key) {
    const int t    = blockIdx.x;
    const int tid  = threadIdx.x;
    const int lane = tid & 63;
    const int w    = tid >> 6;
    const int l15  = lane & 15;
    const int lk8  = (lane >> 4) * 8;
    const int brow = w * 16 + l15;

    const unsigned short* abase = hd + ((size_t)t * 64 + brow) * HIDN;
    f32x4 acc[7];
    #pragma unroll
    for (int nb = 0; nb < 7; ++nb) acc[nb] = (f32x4){0.f, 0.f, 0.f, 0.f};

    #pragma unroll
    for (int kk = 0; kk < 16; ++kk) {
        short8 a = *reinterpret_cast<const short8*>(abase + kk * 32 + lk8);
        #pragma unroll
        for (int nb = 0; nb < 7; ++nb) {
            short8 b = *reinterpret_cast<const short8*>(
                dwb + (size_t)(nb * 16 + l15) * HIDN + kk * 32 + lk8);
            acc[nb] = __builtin_amdgcn_mfma_f32_16x16x32_bf16(a, b, acc[nb], 0, 0, 0);
        }
    }
    #pragma unroll
    for (int nb = 0; nb < 7; ++nb) {
        int n = nb * 16 + l15;
        if (n < EMBD) {
            #pragma unroll
            for (int r = 0; r < 4; ++r) {
                int b = w * 16 + (lane >> 4) * 4 + r;
                u32 u  = __float_as_uint(acc[nb][r]);
                u32 kv = (u & 0x80000000u) ? ~u : (u | 0x80000000u);  // order-preserving
                atomicMax(&key[b * EMBD + n], kv);
            }
        }
    }
}

// ---------------- K5: inverse transform + decoder bias -----------------------
__global__ void k_final(const u32* __restrict__ key, const float* __restrict__ db,
                        float* __restrict__ out) {
    int i = blockIdx.x * 256 + threadIdx.x;
    if (i < BATCH * EMBD) {
        u32 k = key[i];
        u32 u = (k & 0x80000000u) ? (k & 0x7fffffffu) : ~k;
        out[i] = __uint_as_float(u) + db[i % EMBD];
    }
}

extern "C" void kernel_launch(void* const* d_in, const int* in_sizes, int n_in,
                              void* d_out, int out_size, void* d_ws, size_t ws_size,
                              hipStream_t stream) {
    const int*   x   = (const int*)d_in[0];
    const float* emb = (const float*)d_in[1];
    const float* wih = (const float*)d_in[2];
    const float* whh = (const float*)d_in[3];
    const float* bih = (const float*)d_in[4];
    const float* bhh = (const float*)d_in[5];
    const float* gam = (const float*)d_in[6];
    const float* bet = (const float*)d_in[7];
    const float* dw  = (const float*)d_in[8];
    const float* db  = (const float*)d_in[9];
    const float* msk = (const float*)d_in[10];

    char* ws = (char*)d_ws;
    unsigned short* A   = (unsigned short*)(ws + A_OFF);
    unsigned short* hd  = (unsigned short*)(ws + HD_OFF);
    unsigned short* hb  = (unsigned short*)(ws + HB_OFF);
    u32*            flg = (u32*)(ws + FLG_OFF);
    u32*            key = (u32*)(ws + KEY_OFF);
    unsigned short* dwb = (unsigned short*)(ws + DW_OFF);

    hipMemsetAsync(ws + HB_OFF, 0, ZERO_SPAN, stream);      // h ping-pong + flags + keys
    k_dw    <<<224,  256, 0, stream>>>(dw, dwb);
    k_embed <<<8192, 256, 0, stream>>>(x, emb, A);
    k_lstm  <<<NWG,  512, 0, stream>>>(wih, whh, bih, bhh, gam, bet, msk, A, hb, hd, flg);
    k_decode<<<TSEQ, 256, 0, stream>>>(hd, dwb, key);
    k_final <<<25,   256, 0, stream>>>(key, db, (float*)d_out);
}